// Round 15
// baseline (269.406 us; speedup 1.0000x reference)
//
#include <hip/hip_runtime.h>
#include <hip/hip_bf16.h>

// BasketballGNN R15: wave-per-node update MLP (k_upd1) + small tactical kernel (k_tac).
// R14 evidence: k_upd 65us at 8% occupancy -- thread-per-node => 196 blocks (<1/CU),
// ~1 wave/SIMD, pure grid starvation. Wave-per-node gives 8192 waves.
// aggC/CSR pipeline unchanged from R14 (k_aggC ~64us, next round's target).

__device__ inline float bflo(unsigned u){ return __uint_as_float(u << 16); }
__device__ inline float bfhi(unsigned u){ return __uint_as_float(u & 0xffff0000u); }
__device__ inline float gbf(const unsigned short* p){ return __uint_as_float(((unsigned)(*p)) << 16); }
__device__ inline unsigned short f2bu(float f){
  unsigned x = __float_as_uint(f);
  unsigned r = (x + 0x7fffu + ((x >> 16) & 1u)) >> 16;  // RNE
  return (unsigned short)r;
}
__device__ inline unsigned pck(float a, float b){ return (unsigned)f2bu(a) | ((unsigned)f2bu(b) << 16); }
__device__ inline void unpack8(uint4 v, float* f){
  f[0]=bflo(v.x); f[1]=bfhi(v.x); f[2]=bflo(v.y); f[3]=bfhi(v.y);
  f[4]=bflo(v.z); f[5]=bfhi(v.z); f[6]=bflo(v.w); f[7]=bfhi(v.w);
}

// detect edge-index width (int64 -> odd 32b words all zero). 1 = int32, 0 = int64.
__device__ inline int detect_i32(const int* ei, int nwords, int tid, int* sflag){
  if (tid == 0) *sflag = 0;
  __syncthreads();
  int acc = 0;
  for (int i = tid; i < nwords; i += 256)
    if (i & 1) acc |= ei[i];
  if (acc) atomicOr(sflag, 1);
  __syncthreads();
  return *sflag;
}

__device__ inline void load_rc32(const int* ei, int is32, int e, int E, int N, int& r, int& c){
  if (is32){ r = ei[e]; c = ei[(size_t)E + e]; }
  else     { r = ei[2*(size_t)e]; c = ei[2*((size_t)E + (size_t)e)]; }
  r = min(max(r, 0), N-1); c = min(max(c, 0), N-1);
}

// ---------------- k_enc: thread-per-node encoder -> hb (bf16) ----------------
__global__ __launch_bounds__(256) void k_enc(
    const float* __restrict__ x,   // [N,6]
    const float* __restrict__ W1,  // [6,64]
    const float* __restrict__ b1,
    const float* __restrict__ W2,  // [64,64]
    const float* __restrict__ b2,
    unsigned short* __restrict__ hb,  // [N,64] bf16
    int N)
{
  __shared__ float W1s[6*64];
  __shared__ float W2s[64*64];
  __shared__ float b1s[64], b2s[64];
  int tid = threadIdx.x;
  for (int i = tid; i < 6*64; i += 256) W1s[i] = W1[i];
  for (int i = tid; i < 64*64; i += 256) W2s[i] = W2[i];
  if (tid < 64){ b1s[tid] = b1[tid]; b2s[tid] = b2[tid]; }
  __syncthreads();
  int n = blockIdx.x * 256 + tid;
  if (n >= N) return;

  float xv[6];
  #pragma unroll
  for (int k = 0; k < 6; k++) xv[k] = x[(size_t)n*6 + k];

  float acc[64];
  #pragma unroll
  for (int m = 0; m < 64; m++) acc[m] = b2s[m];

  #pragma unroll 1
  for (int j = 0; j < 64; j++){
    float s = b1s[j];
    #pragma unroll
    for (int k = 0; k < 6; k++) s += xv[k] * W1s[k*64 + j];
    s = fmaxf(s, 0.f);
    const float4* w2 = reinterpret_cast<const float4*>(&W2s[j*64]);
    #pragma unroll
    for (int q = 0; q < 16; q++){
      float4 w = w2[q];
      acc[4*q+0] += s*w.x; acc[4*q+1] += s*w.y; acc[4*q+2] += s*w.z; acc[4*q+3] += s*w.w;
    }
  }
  uint4* orow = reinterpret_cast<uint4*>(hb + (size_t)n*64);
  #pragma unroll
  for (int q = 0; q < 8; q++){
    uint4 v;
    v.x = pck(acc[8*q+0], acc[8*q+1]);
    v.y = pck(acc[8*q+2], acc[8*q+3]);
    v.z = pck(acc[8*q+4], acc[8*q+5]);
    v.w = pck(acc[8*q+6], acc[8*q+7]);
    orow[q] = v;
  }
}

// ---------------- k_uv: wave-per-node, msgW1 columns in VGPRs, no LDS ----------------
template<int VPREC>
__global__ __launch_bounds__(256) void k_uv(
    const unsigned short* __restrict__ hb,  // [N,64] bf16
    const float* __restrict__ W1,           // [128,64]
    unsigned short* __restrict__ uh,
    float* __restrict__ vf, unsigned short* __restrict__ vh,
    int N)
{
  int lane = threadIdx.x & 63, w = threadIdx.x >> 6;
  float w1lo[64], w1hi[64];
  #pragma unroll
  for (int k = 0; k < 64; k++) w1lo[k] = W1[k*64 + lane];
  #pragma unroll
  for (int k = 0; k < 64; k++) w1hi[k] = W1[(64+k)*64 + lane];

  for (int node = blockIdx.x*4 + w; node < N; node += gridDim.x*4){
    const unsigned* hp = reinterpret_cast<const unsigned*>(hb + (size_t)node*64);
    unsigned cur[32];
    #pragma unroll
    for (int q = 0; q < 32; q++) cur[q] = hp[q];
    float su = 0.f, sv = 0.f;
    #pragma unroll
    for (int q = 0; q < 32; q++){
      float a = bflo(cur[q]), b = bfhi(cur[q]);
      su += a*w1lo[2*q] + b*w1lo[2*q+1];
      sv += a*w1hi[2*q] + b*w1hi[2*q+1];
    }
    uh[(size_t)node*64 + lane] = f2bu(su);
    if (VPREC) vf[(size_t)node*64 + lane] = sv;
    else       vh[(size_t)node*64 + lane] = f2bu(sv);
  }
}

// ---------------- k_hist: coarse histogram, c-only loads, self-detect ----------------
__global__ __launch_bounds__(256) void k_hist(
    const int* __restrict__ ei,
    int* __restrict__ BH,           // [nb1 * 1024], bin-major, XCD-grouped block order
    int E, int N, int nb1, int nwords)
{
  __shared__ int hist[1024];
  __shared__ int sflag;
  int tid = threadIdx.x;
  for (int i = tid; i < nb1; i += 256) hist[i] = 0;
  int is32 = detect_i32(ei, nwords, tid, &sflag);  // includes syncthreads
  int j = blockIdx.x;
  for (int e = j*256 + tid; e < E; e += 1024*256){
    int c = is32 ? ei[(size_t)E + e] : ei[2*((size_t)E + (size_t)e)];
    c = min(max(c, 0), N-1);
    atomicAdd(&hist[c >> 8], 1);                   // LDS atomic
  }
  __syncthreads();
  int jm = ((j & 7) << 7) | (j >> 3);              // XCD-grouped chunk order
  for (int i = tid; i < nb1; i += 256) BH[(size_t)i*1024 + jm] = hist[i];
}

// ---------------- scans ----------------
__global__ void k_scan1(const int* __restrict__ counts, int* __restrict__ offsets,
                        int* __restrict__ part, int M)
{
  __shared__ int tsum[256];
  int t = threadIdx.x;
  int base = blockIdx.x*2048 + t*8;
  int v[8]; int s = 0;
  #pragma unroll
  for (int i = 0; i < 8; i++){ int idx = base+i; v[i] = (idx < M) ? counts[idx] : 0; }
  #pragma unroll
  for (int i = 0; i < 8; i++){ int t0 = v[i]; v[i] = s; s += t0; }
  tsum[t] = s;
  __syncthreads();
  for (int d = 1; d < 256; d <<= 1){
    int y = (t >= d) ? tsum[t-d] : 0;
    __syncthreads();
    tsum[t] += y;
    __syncthreads();
  }
  int tpre = tsum[t] - s;
  #pragma unroll
  for (int i = 0; i < 8; i++){ int idx = base+i; if (idx < M) offsets[idx] = tpre + v[i]; }
  if (t == 255) part[blockIdx.x] = tsum[255];
}

__global__ void k_scan2(int* __restrict__ part, int nblk, int* __restrict__ offsets, int M, int E)
{
  __shared__ int tmp[256];
  int t = threadIdx.x;
  int v = (t < nblk) ? part[t] : 0;
  tmp[t] = v;
  __syncthreads();
  for (int d = 1; d < 256; d <<= 1){
    int y = (t >= d) ? tmp[t-d] : 0;
    __syncthreads();
    tmp[t] += y;
    __syncthreads();
  }
  if (t < nblk) part[t] = tmp[t] - v;   // exclusive
  if (t == 0) offsets[M] = E;
}

// ------- pass2: scatter to coarse buckets (self-detect; XCD-grouped chunks) -------
__global__ __launch_bounds__(256) void k_pass2(
    const int* __restrict__ ei,
    const int* __restrict__ SO, const int* __restrict__ part,
    unsigned* __restrict__ packed,     // [E]: (c&255)<<24 | r
    int E, int N, int nb1, int nwords)
{
  __shared__ int cur[1024];
  __shared__ int sflag;
  int tid = threadIdx.x;
  int j = blockIdx.x;
  int jm = ((j & 7) << 7) | (j >> 3);
  for (int i = tid; i < nb1; i += 256){
    int idx = i*1024 + jm;
    cur[i] = SO[idx] + part[idx >> 11];
  }
  int is32 = detect_i32(ei, nwords, tid, &sflag);  // includes syncthreads
  for (int e = j*256 + tid; e < E; e += 1024*256){
    int r, c; load_rc32(ei, is32, e, E, N, r, c);
    int bin = c >> 8, low = c & 255;
    int pos = atomicAdd(&cur[bin], 1);             // LDS atomic
    packed[pos] = ((unsigned)low << 24) | (unsigned)r;
  }
}

// ------- pass3: bucket-local counting sort -> node-major CSR (offC, list2) -------
template<typename IT>
__global__ __launch_bounds__(256) void k_pass3(
    const unsigned* __restrict__ packed,
    const int* __restrict__ SO, const int* __restrict__ part,
    int* __restrict__ offC,            // [N+1]
    IT* __restrict__ list2,
    int N, int nb1, int M, int E)
{
  __shared__ int hist[256], scn[256], cur[256];
  int tid = threadIdx.x;
  int bin = blockIdx.x;
  int i0 = bin*1024;
  int i1 = (bin+1)*1024;
  int segStart = SO[i0] + part[i0 >> 11];
  int segEnd   = (i1 >= M) ? E : (SO[i1] + part[i1 >> 11]);

  hist[tid] = 0;
  __syncthreads();
  for (int p = segStart + tid; p < segEnd; p += 256)
    atomicAdd(&hist[packed[p] >> 24], 1);  // LDS atomic
  __syncthreads();
  int own = hist[tid];
  scn[tid] = own;
  __syncthreads();
  for (int d = 1; d < 256; d <<= 1){
    int y = (tid >= d) ? scn[tid-d] : 0;
    __syncthreads();
    scn[tid] += y;
    __syncthreads();
  }
  int excl = scn[tid] - own;
  cur[tid] = excl;
  int node = bin*256 + tid;
  if (node < N) offC[node] = segStart + excl;
  if (bin == nb1-1 && tid == 0) offC[N] = E;
  __syncthreads();
  for (int p = segStart + tid; p < segEnd; p += 256){
    unsigned u = packed[p];
    int pos = atomicAdd(&cur[u >> 24], 1); // LDS atomic
    list2[segStart + pos] = (IT)(u & 0xFFFFFFu);
  }
}

// ------- aggregation: coalesced index load + readlane broadcast (R13, unchanged) -------
template<int VPREC, typename IT>
__global__ __launch_bounds__(256) void k_aggC(
    const unsigned short* __restrict__ uh,  // [N,64] bf16
    const float* vfin, const unsigned short* vhin,
    float* aggf, unsigned short* aggh,
    const float* __restrict__ b1,
    const float* __restrict__ W2,   // [64,64]
    const float* __restrict__ b2,
    const int* __restrict__ offC, const IT* __restrict__ list2, int N)
{
  __shared__ float sS[4][64];
  int lane = threadIdx.x & 63, w = threadIdx.x >> 6;
  float w2c[64];
  #pragma unroll
  for (int j = 0; j < 64; j++) w2c[j] = W2[j*64 + lane];
  float b1l = b1[lane], b2l = b2[lane];

  for (int node = blockIdx.x*4 + w; node < N; node += gridDim.x*4){
    int base = offC[node];
    int deg  = offC[node+1] - base;
    float vc = (VPREC ? vfin[(size_t)node*64 + lane]
                      : gbf(vhin + (size_t)node*64 + lane)) + b1l;

    float acc = 0.f;
    #pragma unroll 1
    for (int cs = 0; cs < deg; cs += 64){
      int clen = min(deg - cs, 64);
      int myidx = (lane < clen) ? (int)list2[base + cs + lane] : 0;  // one coalesced load
      #pragma unroll 1
      for (int s = 0; s < clen; s += 16){
        float zs[16];
        #pragma unroll
        for (int k = 0; k < 16; k++){
          int ss = min(s + k, clen - 1);                       // wave-uniform
          int r  = __builtin_amdgcn_readlane(myidx, ss);       // SGPR index
          zs[k] = gbf(uh + (size_t)r*64 + lane);               // saddr gather
        }
        #pragma unroll
        for (int k = 0; k < 16; k++){
          float rl = fmaxf(zs[k] + vc, 0.f);
          acc += (s + k < clen) ? rl : 0.f;                    // predicated accumulate
        }
      }
    }

    float mr = (deg > 0) ? acc/(float)deg : 0.f;
    sS[w][lane] = mr;
    const float4* s4 = reinterpret_cast<const float4*>(&sS[w][0]);
    float m = b2l;
    #pragma unroll
    for (int q = 0; q < 16; q++){
      float4 v4 = s4[q];
      m += v4.x*w2c[4*q+0] + v4.y*w2c[4*q+1] + v4.z*w2c[4*q+2] + v4.w*w2c[4*q+3];
    }
    if (deg == 0) m = 0.f;
    if (VPREC) aggf[(size_t)node*64 + lane] = m;
    else       aggh[(size_t)node*64 + lane] = f2bu(m);
  }
}

// ------- k_upd1: wave-per-node update MLP; h2 -> out[n*32..] directly -------
template<int VPREC>
__global__ __launch_bounds__(256) void k_upd1(
    const unsigned short* __restrict__ hb,   // [N,64] bf16
    const float* aggf, const unsigned short* aggh,
    const float* __restrict__ uW1,   // [128,64]
    const float* __restrict__ ub1,   // [64]
    const float* __restrict__ uW2,   // [64,32]
    const float* __restrict__ ub2,   // [32]
    float* out, int N)
{
  __shared__ float featS[4][128];
  __shared__ float sS[4][64];
  int tid = threadIdx.x, lane = tid & 63, w = tid >> 6, l5 = lane & 31;

  float u1c[128];
  #pragma unroll
  for (int k = 0; k < 128; k++) u1c[k] = uW1[k*64 + lane];
  float u2c[64];
  #pragma unroll
  for (int j = 0; j < 64; j++) u2c[j] = uW2[j*32 + l5];
  float b1l = ub1[lane], b2l = ub2[l5];

  for (int node = blockIdx.x*4 + w; node < N; node += gridDim.x*4){
    // assemble feat = [h(64) ; agg(64)] in per-wave LDS slice (in-wave DS order)
    const unsigned* h32 = reinterpret_cast<const unsigned*>(hb) + (size_t)node*32;
    if (lane < 32){
      unsigned d = h32[lane];
      float2 f2; f2.x = bflo(d); f2.y = bfhi(d);
      *reinterpret_cast<float2*>(&featS[w][2*lane]) = f2;
    }
    float av = VPREC ? aggf[(size_t)node*64 + lane] : gbf(aggh + (size_t)node*64 + lane);
    featS[w][64 + lane] = av;

    float s = b1l;
    const float4* f4 = reinterpret_cast<const float4*>(&featS[w][0]);
    #pragma unroll
    for (int q = 0; q < 32; q++){
      float4 f = f4[q];
      s += f.x*u1c[4*q+0] + f.y*u1c[4*q+1] + f.z*u1c[4*q+2] + f.w*u1c[4*q+3];
    }
    s = fmaxf(s, 0.f);
    sS[w][lane] = s;

    float m = b2l;
    const float4* s4 = reinterpret_cast<const float4*>(&sS[w][0]);
    #pragma unroll
    for (int q = 0; q < 16; q++){
      float4 sv = s4[q];
      m += sv.x*u2c[4*q+0] + sv.y*u2c[4*q+1] + sv.z*u2c[4*q+2] + sv.w*u2c[4*q+3];
    }
    if (lane < 32) out[(size_t)node*32 + l5] = m;
  }
}

// ------- k_tac: thread-per-node tactical head (reads h2 from out) -------
__global__ __launch_bounds__(256) void k_tac(
    const float* __restrict__ tW1, const float* __restrict__ tb1,  // [32,64],[64]
    const float* __restrict__ tW2, const float* __restrict__ tb2,  // [64,16],[16]
    const float* __restrict__ tW3, const float* __restrict__ tb3,  // [16,4],[4]
    float* out, int N)
{
  __shared__ float tW1s[32*64];
  __shared__ float tW2s[64*16];
  __shared__ float tW3s[64];
  __shared__ float tb1s[64], tb2s[16], tb3s[4];
  int tid = threadIdx.x;
  for (int i = tid; i < 32*64; i += 256) tW1s[i] = tW1[i];
  for (int i = tid; i < 64*16; i += 256) tW2s[i] = tW2[i];
  if (tid < 64){ tb1s[tid] = tb1[tid]; tW3s[tid] = tW3[tid]; }
  if (tid < 16) tb2s[tid] = tb2[tid];
  if (tid < 4)  tb3s[tid] = tb3[tid];
  __syncthreads();
  int n = blockIdx.x * 256 + tid;
  if (n >= N) return;

  float h2[32];
  const float4* hp = reinterpret_cast<const float4*>(out + (size_t)n*32);
  #pragma unroll
  for (int q = 0; q < 8; q++){
    float4 v = hp[q];
    h2[4*q+0]=v.x; h2[4*q+1]=v.y; h2[4*q+2]=v.z; h2[4*q+3]=v.w;
  }

  float t2[16];
  #pragma unroll
  for (int m = 0; m < 16; m++) t2[m] = 0.f;
  #pragma unroll 1
  for (int j = 0; j < 64; j++){
    float s = tb1s[j];
    #pragma unroll
    for (int k = 0; k < 32; k++) s += h2[k] * tW1s[k*64 + j];
    s = fmaxf(s, 0.f);
    #pragma unroll
    for (int m = 0; m < 16; m++) t2[m] += s * tW2s[j*16 + m];
  }
  float o[4];
  #pragma unroll
  for (int q = 0; q < 4; q++) o[q] = tb3s[q];
  #pragma unroll
  for (int m = 0; m < 16; m++){
    float tm = fmaxf(t2[m] + tb2s[m], 0.f);
    #pragma unroll
    for (int q = 0; q < 4; q++) o[q] += tm * tW3s[m*4 + q];
  }
  float4* o2 = reinterpret_cast<float4*>(out + (size_t)N*32 + (size_t)n*4);
  float4 vv; vv.x = o[0]; vv.y = o[1]; vv.z = o[2]; vv.w = o[3];
  *o2 = vv;
}

extern "C" void kernel_launch(void* const* d_in, const int* in_sizes, int n_in,
                              void* d_out, int out_size, void* d_ws, size_t ws_size,
                              hipStream_t stream)
{
  const float* x     = (const float*)d_in[0];
  const int*   ei    = (const int*)d_in[1];
  const float* encW1 = (const float*)d_in[2];
  const float* encb1 = (const float*)d_in[3];
  const float* encW2 = (const float*)d_in[4];
  const float* encb2 = (const float*)d_in[5];
  const float* msgW1 = (const float*)d_in[6];
  const float* msgb1 = (const float*)d_in[7];
  const float* msgW2 = (const float*)d_in[8];
  const float* msgb2 = (const float*)d_in[9];
  const float* updW1 = (const float*)d_in[10];
  const float* updb1 = (const float*)d_in[11];
  const float* updW2 = (const float*)d_in[12];
  const float* updb2 = (const float*)d_in[13];
  const float* tacW1 = (const float*)d_in[14];
  const float* tacb1 = (const float*)d_in[15];
  const float* tacW2 = (const float*)d_in[16];
  const float* tacb2 = (const float*)d_in[17];
  const float* tacW3 = (const float*)d_in[18];
  const float* tacb3 = (const float*)d_in[19];

  int N = in_sizes[0] / 6;
  int E = in_sizes[1] / 2;
  float* out = (float*)d_out;
  int idx16 = (N <= 65535) ? 1 : 0;
  int nwords = (2*E < 8192) ? 2*E : 8192;   // int-width detect window

  int nb1 = (N + 255) >> 8;            // coarse buckets (c>>8); 196 for N=50k
  const int G1 = 1024;                 // hist/pass2 grid (jmap hardcodes 1024)
  int M   = nb1 * G1;

  auto align = [](size_t v){ return (v + 255) & ~(size_t)255; };
  size_t hbB = (size_t)N*64*2, uhB = (size_t)N*64*2;
  size_t list2B = (size_t)E * (idx16 ? 2 : 4);
  auto tail = [&](size_t o){
    o = align(o); o += (size_t)M*4;          // BH
    o = align(o); o += (size_t)(M+1)*4;      // SO
    o = align(o); o += 256*4;                // part
    o = align(o); o += (size_t)(N+1)*4;      // offC
    o = align(o); o += list2B;               // list2
    return o;
  };
  size_t total2 = tail(align(align(hbB) + uhB) + (size_t)N*64*4);  // v f32
  int VPREC = (ws_size >= total2) ? 1 : 0;

  char* ws = (char*)d_ws;
  size_t o = 0;
  unsigned short* hb = (unsigned short*)(ws + o); o = align(o + hbB);
  unsigned short* uh = (unsigned short*)(ws + o); o = align(o + uhB);
  float* vf = nullptr; unsigned short* vh = nullptr;
  if (VPREC){ vf = (float*)(ws + o);          o = align(o + (size_t)N*64*4); }
  else      { vh = (unsigned short*)(ws + o); o = align(o + (size_t)N*64*2); }
  int* BH   = (int*)(ws + o); o = align(o + (size_t)M*4);
  int* SO   = (int*)(ws + o); o = align(o + (size_t)(M+1)*4);
  int* part = (int*)(ws + o); o = align(o + 256*4);
  int* offC = (int*)(ws + o); o = align(o + (size_t)(N+1)*4);
  void* list2P = (void*)(ws + o); o = align(o + list2B);
  unsigned* packed = (unsigned*)out;   // d_out scratch [E u32]; dead before k_upd1

  dim3 blk(256);
  int nblkN  = (N + 255) / 256;        // 196
  int nblkS1 = (M + 2047) / 2048;      // 98 (<=256 req by k_scan2)

  k_enc <<<dim3(nblkN), blk, 0, stream>>>(x, encW1, encb1, encW2, encb2, hb, N);
  if (VPREC) k_uv<1><<<dim3(2048), blk, 0, stream>>>(hb, msgW1, uh, vf, vh, N);
  else       k_uv<0><<<dim3(2048), blk, 0, stream>>>(hb, msgW1, uh, vf, vh, N);
  k_hist<<<dim3(G1), blk, 0, stream>>>(ei, BH, E, N, nb1, nwords);
  k_scan1<<<dim3(nblkS1), blk, 0, stream>>>(BH, SO, part, M);
  k_scan2<<<dim3(1),      blk, 0, stream>>>(part, nblkS1, SO, M, E);
  k_pass2<<<dim3(G1),     blk, 0, stream>>>(ei, SO, part, packed, E, N, nb1, nwords);
  if (idx16){
    k_pass3<unsigned short><<<dim3(nb1), blk, 0, stream>>>(packed, SO, part, offC, (unsigned short*)list2P, N, nb1, M, E);
    if (VPREC) k_aggC<1,unsigned short><<<dim3(2048), blk, 0, stream>>>(uh, vf, vh, vf, vh, msgb1, msgW2, msgb2, offC, (unsigned short*)list2P, N);
    else       k_aggC<0,unsigned short><<<dim3(2048), blk, 0, stream>>>(uh, vf, vh, vf, vh, msgb1, msgW2, msgb2, offC, (unsigned short*)list2P, N);
  } else {
    k_pass3<int><<<dim3(nb1), blk, 0, stream>>>(packed, SO, part, offC, (int*)list2P, N, nb1, M, E);
    if (VPREC) k_aggC<1,int><<<dim3(2048), blk, 0, stream>>>(uh, vf, vh, vf, vh, msgb1, msgW2, msgb2, offC, (int*)list2P, N);
    else       k_aggC<0,int><<<dim3(2048), blk, 0, stream>>>(uh, vf, vh, vf, vh, msgb1, msgW2, msgb2, offC, (int*)list2P, N);
  }
  if (VPREC) k_upd1<1><<<dim3(2048), blk, 0, stream>>>(hb, vf, vh, updW1, updb1, updW2, updb2, out, N);
  else       k_upd1<0><<<dim3(2048), blk, 0, stream>>>(hb, vf, vh, updW1, updb1, updW2, updb2, out, N);
  k_tac<<<dim3(nblkN), blk, 0, stream>>>(tacW1, tacb1, tacW2, tacb2, tacW3, tacb3, out, N);
}

// Round 16
// 237.948 us; speedup vs baseline: 1.1322x; 1.1322x over previous
//
#include <hip/hip_runtime.h>
#include <hip/hip_bf16.h>

// BasketballGNN R16: (1) k_encuv2 = enc+u,v+hist fused, wave-per-node, weights-in-VGPR,
// broadcast-b128 LDS for cross-lane vectors (R13's fusion win without its 196-block
// starvation). (2) k_aggV = dwordx4 gathers (8 rows/mem-instr vs 1) + shfl row
// broadcast + xor-reduce. Kernel count 11 -> 8 (launch gaps ~10-15us each).

__device__ inline float bflo(unsigned u){ return __uint_as_float(u << 16); }
__device__ inline float bfhi(unsigned u){ return __uint_as_float(u & 0xffff0000u); }
__device__ inline float gbf(const unsigned short* p){ return __uint_as_float(((unsigned)(*p)) << 16); }
__device__ inline unsigned short f2bu(float f){
  unsigned x = __float_as_uint(f);
  unsigned r = (x + 0x7fffu + ((x >> 16) & 1u)) >> 16;  // RNE
  return (unsigned short)r;
}
__device__ inline unsigned pck(float a, float b){ return (unsigned)f2bu(a) | ((unsigned)f2bu(b) << 16); }

// detect edge-index width (int64 -> odd 32b words all zero). 1 = int32, 0 = int64.
__device__ inline int detect_i32(const int* ei, int nwords, int tid, int* sflag){
  if (tid == 0) *sflag = 0;
  __syncthreads();
  int acc = 0;
  for (int i = tid; i < nwords; i += 256)
    if (i & 1) acc |= ei[i];
  if (acc) atomicOr(sflag, 1);
  __syncthreads();
  return *sflag;
}

__device__ inline void load_rc32(const int* ei, int is32, int e, int E, int N, int& r, int& c){
  if (is32){ r = ei[e]; c = ei[(size_t)E + e]; }
  else     { r = ei[2*(size_t)e]; c = ei[2*((size_t)E + (size_t)e)]; }
  r = min(max(r, 0), N-1); c = min(max(c, 0), N-1);
}

// ------- k_encuv2: wave-per-node enc -> hb; u,v; + hist edge phase -------
template<int VPREC>
__global__ __launch_bounds__(256) void k_encuv2(
    const float* __restrict__ x,    // [N,6]
    const float* __restrict__ eW1, const float* __restrict__ eb1,
    const float* __restrict__ eW2, const float* __restrict__ eb2,
    const float* __restrict__ mW1,  // [128,64]
    unsigned short* __restrict__ hb,
    unsigned short* __restrict__ uh,
    float* __restrict__ vf, unsigned short* __restrict__ vh,
    int N,
    const int* __restrict__ ei,
    int* __restrict__ BH,           // [nb1*1024] bin-major, XCD-grouped block order
    int E, int nb1, int nwords)
{
  __shared__ float sS[4][64];
  __shared__ int   hist[1024];
  __shared__ int   sflag;
  int tid = threadIdx.x, lane = tid & 63, w = tid >> 6;

  // persistent per-lane weight columns
  float eW1c[6];
  #pragma unroll
  for (int k = 0; k < 6; k++) eW1c[k] = eW1[k*64 + lane];
  float eW2c[64];
  #pragma unroll
  for (int j = 0; j < 64; j++) eW2c[j] = eW2[j*64 + lane];
  float m1lo[64], m1hi[64];
  #pragma unroll
  for (int k = 0; k < 64; k++) m1lo[k] = mW1[k*64 + lane];
  #pragma unroll
  for (int k = 0; k < 64; k++) m1hi[k] = mW1[(64+k)*64 + lane];
  float eb1l = eb1[lane], eb2l = eb2[lane];

  // node phase (wave-per-node)
  for (int node = blockIdx.x*4 + w; node < N; node += gridDim.x*4){
    float xv[6];
    #pragma unroll
    for (int k = 0; k < 6; k++) xv[k] = x[(size_t)node*6 + k];  // wave-uniform

    float a = eb1l;
    #pragma unroll
    for (int k = 0; k < 6; k++) a += xv[k] * eW1c[k];
    a = fmaxf(a, 0.f);
    sS[w][lane] = a;                         // in-wave DS order
    const float4* s4 = reinterpret_cast<const float4*>(&sS[w][0]);
    float h = eb2l;
    #pragma unroll
    for (int q = 0; q < 16; q++){
      float4 f = s4[q];                      // broadcast read
      h += f.x*eW2c[4*q+0] + f.y*eW2c[4*q+1] + f.z*eW2c[4*q+2] + f.w*eW2c[4*q+3];
    }
    hb[(size_t)node*64 + lane] = f2bu(h);
    sS[w][lane] = h;                         // overwrite after all reads (lockstep)
    float su = 0.f, sv = 0.f;
    #pragma unroll
    for (int q = 0; q < 16; q++){
      float4 f = s4[q];                      // broadcast read (h)
      su += f.x*m1lo[4*q+0] + f.y*m1lo[4*q+1] + f.z*m1lo[4*q+2] + f.w*m1lo[4*q+3];
      sv += f.x*m1hi[4*q+0] + f.y*m1hi[4*q+1] + f.z*m1hi[4*q+2] + f.w*m1hi[4*q+3];
    }
    uh[(size_t)node*64 + lane] = f2bu(su);
    if (VPREC) vf[(size_t)node*64 + lane] = sv;
    else       vh[(size_t)node*64 + lane] = f2bu(sv);
  }

  // edge phase: coarse histogram (c-only loads)
  for (int i = tid; i < nb1; i += 256) hist[i] = 0;
  int is32 = detect_i32(ei, nwords, tid, &sflag);  // includes barriers
  int j = blockIdx.x;
  for (int e = j*256 + tid; e < E; e += 1024*256){
    int c = is32 ? ei[(size_t)E + e] : ei[2*((size_t)E + (size_t)e)];
    c = min(max(c, 0), N-1);
    atomicAdd(&hist[c >> 8], 1);                   // LDS atomic
  }
  __syncthreads();
  int jm = ((j & 7) << 7) | (j >> 3);              // XCD-grouped chunk order
  for (int i = tid; i < nb1; i += 256) BH[(size_t)i*1024 + jm] = hist[i];
}

// ---------------- scans ----------------
__global__ void k_scan1(const int* __restrict__ counts, int* __restrict__ offsets,
                        int* __restrict__ part, int M)
{
  __shared__ int tsum[256];
  int t = threadIdx.x;
  int base = blockIdx.x*2048 + t*8;
  int v[8]; int s = 0;
  #pragma unroll
  for (int i = 0; i < 8; i++){ int idx = base+i; v[i] = (idx < M) ? counts[idx] : 0; }
  #pragma unroll
  for (int i = 0; i < 8; i++){ int t0 = v[i]; v[i] = s; s += t0; }
  tsum[t] = s;
  __syncthreads();
  for (int d = 1; d < 256; d <<= 1){
    int y = (t >= d) ? tsum[t-d] : 0;
    __syncthreads();
    tsum[t] += y;
    __syncthreads();
  }
  int tpre = tsum[t] - s;
  #pragma unroll
  for (int i = 0; i < 8; i++){ int idx = base+i; if (idx < M) offsets[idx] = tpre + v[i]; }
  if (t == 255) part[blockIdx.x] = tsum[255];
}

__global__ void k_scan2(int* __restrict__ part, int nblk, int* __restrict__ offsets, int M, int E)
{
  __shared__ int tmp[256];
  int t = threadIdx.x;
  int v = (t < nblk) ? part[t] : 0;
  tmp[t] = v;
  __syncthreads();
  for (int d = 1; d < 256; d <<= 1){
    int y = (t >= d) ? tmp[t-d] : 0;
    __syncthreads();
    tmp[t] += y;
    __syncthreads();
  }
  if (t < nblk) part[t] = tmp[t] - v;   // exclusive
  if (t == 0) offsets[M] = E;
}

// ------- pass2: scatter to coarse buckets -------
__global__ __launch_bounds__(256) void k_pass2(
    const int* __restrict__ ei,
    const int* __restrict__ SO, const int* __restrict__ part,
    unsigned* __restrict__ packed,     // [E]: (c&255)<<24 | r
    int E, int N, int nb1, int nwords)
{
  __shared__ int cur[1024];
  __shared__ int sflag;
  int tid = threadIdx.x;
  int j = blockIdx.x;
  int jm = ((j & 7) << 7) | (j >> 3);
  for (int i = tid; i < nb1; i += 256){
    int idx = i*1024 + jm;
    cur[i] = SO[idx] + part[idx >> 11];
  }
  int is32 = detect_i32(ei, nwords, tid, &sflag);
  for (int e = j*256 + tid; e < E; e += 1024*256){
    int r, c; load_rc32(ei, is32, e, E, N, r, c);
    int bin = c >> 8, low = c & 255;
    int pos = atomicAdd(&cur[bin], 1);             // LDS atomic
    packed[pos] = ((unsigned)low << 24) | (unsigned)r;
  }
}

// ------- pass3: bucket-local counting sort -> node-major CSR -------
template<typename IT>
__global__ __launch_bounds__(256) void k_pass3(
    const unsigned* __restrict__ packed,
    const int* __restrict__ SO, const int* __restrict__ part,
    int* __restrict__ offC,            // [N+1]
    IT* __restrict__ list2,
    int N, int nb1, int M, int E)
{
  __shared__ int hist[256], scn[256], cur[256];
  int tid = threadIdx.x;
  int bin = blockIdx.x;
  int i0 = bin*1024;
  int i1 = (bin+1)*1024;
  int segStart = SO[i0] + part[i0 >> 11];
  int segEnd   = (i1 >= M) ? E : (SO[i1] + part[i1 >> 11]);

  hist[tid] = 0;
  __syncthreads();
  for (int p = segStart + tid; p < segEnd; p += 256)
    atomicAdd(&hist[packed[p] >> 24], 1);
  __syncthreads();
  int own = hist[tid];
  scn[tid] = own;
  __syncthreads();
  for (int d = 1; d < 256; d <<= 1){
    int y = (tid >= d) ? scn[tid-d] : 0;
    __syncthreads();
    scn[tid] += y;
    __syncthreads();
  }
  int excl = scn[tid] - own;
  cur[tid] = excl;
  int node = bin*256 + tid;
  if (node < N) offC[node] = segStart + excl;
  if (bin == nb1-1 && tid == 0) offC[N] = E;
  __syncthreads();
  for (int p = segStart + tid; p < segEnd; p += 256){
    unsigned u = packed[p];
    int pos = atomicAdd(&cur[u >> 24], 1);
    list2[segStart + pos] = (IT)(u & 0xFFFFFFu);
  }
}

// ------- k_aggV: vectorized aggregation. lane = (row-slot l>>3, feat-octet l&7).
// One dwordx4 gather = 8 bf16 features of one row; wave covers 8 rows/mem-instr. -------
template<int VPREC, typename IT>
__global__ __launch_bounds__(256) void k_aggV(
    const unsigned short* __restrict__ uh,  // [N,64] bf16
    const float* vfin, const unsigned short* vhin,
    float* aggf, unsigned short* aggh,
    const float* __restrict__ b1,
    const float* __restrict__ W2,   // [64,64]
    const float* __restrict__ b2,
    const int* __restrict__ offC, const IT* __restrict__ list2, int N)
{
  __shared__ float sS[4][64];
  int tid = threadIdx.x, lane = tid & 63, w = tid >> 6;
  int rsub = lane >> 3, fo = lane & 7;      // row slot, feature octet
  float w2c[64];
  #pragma unroll
  for (int j = 0; j < 64; j++) w2c[j] = W2[j*64 + lane];
  float b2l = b2[lane];
  float b1o[8];
  #pragma unroll
  for (int k = 0; k < 8; k++) b1o[k] = b1[fo*8 + k];

  for (int node = blockIdx.x*4 + w; node < N; node += gridDim.x*4){
    int base = offC[node];
    int deg  = offC[node+1] - base;

    float vc8[8];
    #pragma unroll
    for (int k = 0; k < 8; k++)
      vc8[k] = (VPREC ? vfin[(size_t)node*64 + fo*8 + k]
                      : gbf(vhin + (size_t)node*64 + fo*8 + k)) + b1o[k];

    float acc8[8];
    #pragma unroll
    for (int k = 0; k < 8; k++) acc8[k] = 0.f;

    #pragma unroll 1
    for (int cs = 0; cs < deg; cs += 64){
      int clen = min(deg - cs, 64);
      int myidx = (lane < clen) ? (int)list2[base + cs + lane] : 0;
      #pragma unroll 1
      for (int s = 0; s < clen; s += 8){
        int ss = min(s + rsub, clen - 1);
        int r  = __shfl(myidx, ss);                         // row index for my slot
        bool valid = (s + rsub) < clen;
        const uint4* up = reinterpret_cast<const uint4*>(uh + (size_t)r*64 + fo*8);
        uint4 d = *up;                                      // 8 bf16 features
        float f0 = bflo(d.x), f1 = bfhi(d.x), f2 = bflo(d.y), f3 = bfhi(d.y);
        float f4 = bflo(d.z), f5 = bfhi(d.z), f6 = bflo(d.w), f7 = bfhi(d.w);
        float r0 = fmaxf(f0 + vc8[0], 0.f), r1 = fmaxf(f1 + vc8[1], 0.f);
        float r2 = fmaxf(f2 + vc8[2], 0.f), r3 = fmaxf(f3 + vc8[3], 0.f);
        float r4 = fmaxf(f4 + vc8[4], 0.f), r5 = fmaxf(f5 + vc8[5], 0.f);
        float r6 = fmaxf(f6 + vc8[6], 0.f), r7 = fmaxf(f7 + vc8[7], 0.f);
        if (valid){
          acc8[0] += r0; acc8[1] += r1; acc8[2] += r2; acc8[3] += r3;
          acc8[4] += r4; acc8[5] += r5; acc8[6] += r6; acc8[7] += r7;
        }
      }
    }

    // reduce over the 8 row slots (lanes with same fo): xor 8,16,32
    #pragma unroll
    for (int m = 8; m < 64; m <<= 1){
      #pragma unroll
      for (int k = 0; k < 8; k++) acc8[k] += __shfl_xor(acc8[k], m);
    }
    float inv = (deg > 0) ? 1.0f/(float)deg : 0.f;
    if (rsub == 0){
      float4 a, b;
      a.x = acc8[0]*inv; a.y = acc8[1]*inv; a.z = acc8[2]*inv; a.w = acc8[3]*inv;
      b.x = acc8[4]*inv; b.y = acc8[5]*inv; b.z = acc8[6]*inv; b.w = acc8[7]*inv;
      float4* sp = reinterpret_cast<float4*>(&sS[w][fo*8]);
      sp[0] = a; sp[1] = b;
    }
    // final: m = W2^T mean + b2 (broadcast reads)
    const float4* s4 = reinterpret_cast<const float4*>(&sS[w][0]);
    float m = b2l;
    #pragma unroll
    for (int q = 0; q < 16; q++){
      float4 v4 = s4[q];
      m += v4.x*w2c[4*q+0] + v4.y*w2c[4*q+1] + v4.z*w2c[4*q+2] + v4.w*w2c[4*q+3];
    }
    if (deg == 0) m = 0.f;
    if (VPREC) aggf[(size_t)node*64 + lane] = m;
    else       aggh[(size_t)node*64 + lane] = f2bu(m);
  }
}

// ------- k_upd1: wave-per-node update MLP; h2 -> out[n*32..] directly -------
template<int VPREC>
__global__ __launch_bounds__(256) void k_upd1(
    const unsigned short* __restrict__ hb,   // [N,64] bf16
    const float* aggf, const unsigned short* aggh,
    const float* __restrict__ uW1,   // [128,64]
    const float* __restrict__ ub1,   // [64]
    const float* __restrict__ uW2,   // [64,32]
    const float* __restrict__ ub2,   // [32]
    float* out, int N)
{
  __shared__ float featS[4][128];
  __shared__ float sS[4][64];
  int tid = threadIdx.x, lane = tid & 63, w = tid >> 6, l5 = lane & 31;

  float u1c[128];
  #pragma unroll
  for (int k = 0; k < 128; k++) u1c[k] = uW1[k*64 + lane];
  float u2c[64];
  #pragma unroll
  for (int j = 0; j < 64; j++) u2c[j] = uW2[j*32 + l5];
  float b1l = ub1[lane], b2l = ub2[l5];

  for (int node = blockIdx.x*4 + w; node < N; node += gridDim.x*4){
    const unsigned* h32 = reinterpret_cast<const unsigned*>(hb) + (size_t)node*32;
    if (lane < 32){
      unsigned d = h32[lane];
      float2 f2; f2.x = bflo(d); f2.y = bfhi(d);
      *reinterpret_cast<float2*>(&featS[w][2*lane]) = f2;
    }
    float av = VPREC ? aggf[(size_t)node*64 + lane] : gbf(aggh + (size_t)node*64 + lane);
    featS[w][64 + lane] = av;

    float s = b1l;
    const float4* f4 = reinterpret_cast<const float4*>(&featS[w][0]);
    #pragma unroll
    for (int q = 0; q < 32; q++){
      float4 f = f4[q];
      s += f.x*u1c[4*q+0] + f.y*u1c[4*q+1] + f.z*u1c[4*q+2] + f.w*u1c[4*q+3];
    }
    s = fmaxf(s, 0.f);
    sS[w][lane] = s;

    float m = b2l;
    const float4* s4 = reinterpret_cast<const float4*>(&sS[w][0]);
    #pragma unroll
    for (int q = 0; q < 16; q++){
      float4 sv = s4[q];
      m += sv.x*u2c[4*q+0] + sv.y*u2c[4*q+1] + sv.z*u2c[4*q+2] + sv.w*u2c[4*q+3];
    }
    if (lane < 32) out[(size_t)node*32 + l5] = m;
  }
}

// ------- k_tac: thread-per-node tactical head (reads h2 from out) -------
__global__ __launch_bounds__(256) void k_tac(
    const float* __restrict__ tW1, const float* __restrict__ tb1,
    const float* __restrict__ tW2, const float* __restrict__ tb2,
    const float* __restrict__ tW3, const float* __restrict__ tb3,
    float* out, int N)
{
  __shared__ float tW1s[32*64];
  __shared__ float tW2s[64*16];
  __shared__ float tW3s[64];
  __shared__ float tb1s[64], tb2s[16], tb3s[4];
  int tid = threadIdx.x;
  for (int i = tid; i < 32*64; i += 256) tW1s[i] = tW1[i];
  for (int i = tid; i < 64*16; i += 256) tW2s[i] = tW2[i];
  if (tid < 64){ tb1s[tid] = tb1[tid]; tW3s[tid] = tW3[tid]; }
  if (tid < 16) tb2s[tid] = tb2[tid];
  if (tid < 4)  tb3s[tid] = tb3[tid];
  __syncthreads();
  int n = blockIdx.x * 256 + tid;
  if (n >= N) return;

  float h2[32];
  const float4* hp = reinterpret_cast<const float4*>(out + (size_t)n*32);
  #pragma unroll
  for (int q = 0; q < 8; q++){
    float4 v = hp[q];
    h2[4*q+0]=v.x; h2[4*q+1]=v.y; h2[4*q+2]=v.z; h2[4*q+3]=v.w;
  }

  float t2[16];
  #pragma unroll
  for (int m = 0; m < 16; m++) t2[m] = 0.f;
  #pragma unroll 1
  for (int j = 0; j < 64; j++){
    float s = tb1s[j];
    #pragma unroll
    for (int k = 0; k < 32; k++) s += h2[k] * tW1s[k*64 + j];
    s = fmaxf(s, 0.f);
    #pragma unroll
    for (int m = 0; m < 16; m++) t2[m] += s * tW2s[j*16 + m];
  }
  float o[4];
  #pragma unroll
  for (int q = 0; q < 4; q++) o[q] = tb3s[q];
  #pragma unroll
  for (int m = 0; m < 16; m++){
    float tm = fmaxf(t2[m] + tb2s[m], 0.f);
    #pragma unroll
    for (int q = 0; q < 4; q++) o[q] += tm * tW3s[m*4 + q];
  }
  float4* o2 = reinterpret_cast<float4*>(out + (size_t)N*32 + (size_t)n*4);
  float4 vv; vv.x = o[0]; vv.y = o[1]; vv.z = o[2]; vv.w = o[3];
  *o2 = vv;
}

extern "C" void kernel_launch(void* const* d_in, const int* in_sizes, int n_in,
                              void* d_out, int out_size, void* d_ws, size_t ws_size,
                              hipStream_t stream)
{
  const float* x     = (const float*)d_in[0];
  const int*   ei    = (const int*)d_in[1];
  const float* encW1 = (const float*)d_in[2];
  const float* encb1 = (const float*)d_in[3];
  const float* encW2 = (const float*)d_in[4];
  const float* encb2 = (const float*)d_in[5];
  const float* msgW1 = (const float*)d_in[6];
  const float* msgb1 = (const float*)d_in[7];
  const float* msgW2 = (const float*)d_in[8];
  const float* msgb2 = (const float*)d_in[9];
  const float* updW1 = (const float*)d_in[10];
  const float* updb1 = (const float*)d_in[11];
  const float* updW2 = (const float*)d_in[12];
  const float* updb2 = (const float*)d_in[13];
  const float* tacW1 = (const float*)d_in[14];
  const float* tacb1 = (const float*)d_in[15];
  const float* tacW2 = (const float*)d_in[16];
  const float* tacb2 = (const float*)d_in[17];
  const float* tacW3 = (const float*)d_in[18];
  const float* tacb3 = (const float*)d_in[19];

  int N = in_sizes[0] / 6;
  int E = in_sizes[1] / 2;
  float* out = (float*)d_out;
  int idx16 = (N <= 65535) ? 1 : 0;
  int nwords = (2*E < 8192) ? 2*E : 8192;

  int nb1 = (N + 255) >> 8;            // 196 for N=50k
  const int G1 = 1024;                 // jm hardcodes 1024
  int M   = nb1 * G1;

  auto align = [](size_t v){ return (v + 255) & ~(size_t)255; };
  size_t hbB = (size_t)N*64*2, uhB = (size_t)N*64*2;
  size_t list2B = (size_t)E * (idx16 ? 2 : 4);
  auto tail = [&](size_t o){
    o = align(o); o += (size_t)M*4;          // BH
    o = align(o); o += (size_t)(M+1)*4;      // SO
    o = align(o); o += 256*4;                // part
    o = align(o); o += (size_t)(N+1)*4;      // offC
    o = align(o); o += list2B;               // list2
    return o;
  };
  size_t total2 = tail(align(align(hbB) + uhB) + (size_t)N*64*4);
  int VPREC = (ws_size >= total2) ? 1 : 0;

  char* ws = (char*)d_ws;
  size_t o = 0;
  unsigned short* hb = (unsigned short*)(ws + o); o = align(o + hbB);
  unsigned short* uh = (unsigned short*)(ws + o); o = align(o + uhB);
  float* vf = nullptr; unsigned short* vh = nullptr;
  if (VPREC){ vf = (float*)(ws + o);          o = align(o + (size_t)N*64*4); }
  else      { vh = (unsigned short*)(ws + o); o = align(o + (size_t)N*64*2); }
  int* BH   = (int*)(ws + o); o = align(o + (size_t)M*4);
  int* SO   = (int*)(ws + o); o = align(o + (size_t)(M+1)*4);
  int* part = (int*)(ws + o); o = align(o + 256*4);
  int* offC = (int*)(ws + o); o = align(o + (size_t)(N+1)*4);
  void* list2P = (void*)(ws + o); o = align(o + list2B);
  unsigned* packed = (unsigned*)out;   // d_out scratch; dead before k_upd1

  dim3 blk(256);
  int nblkN  = (N + 255) / 256;        // 196
  int nblkS1 = (M + 2047) / 2048;      // 98 (<=256 req by k_scan2)

  if (VPREC) k_encuv2<1><<<dim3(G1), blk, 0, stream>>>(x, encW1, encb1, encW2, encb2, msgW1,
                                                       hb, uh, vf, vh, N, ei, BH, E, nb1, nwords);
  else       k_encuv2<0><<<dim3(G1), blk, 0, stream>>>(x, encW1, encb1, encW2, encb2, msgW1,
                                                       hb, uh, vf, vh, N, ei, BH, E, nb1, nwords);
  k_scan1<<<dim3(nblkS1), blk, 0, stream>>>(BH, SO, part, M);
  k_scan2<<<dim3(1),      blk, 0, stream>>>(part, nblkS1, SO, M, E);
  k_pass2<<<dim3(G1),     blk, 0, stream>>>(ei, SO, part, packed, E, N, nb1, nwords);
  if (idx16){
    k_pass3<unsigned short><<<dim3(nb1), blk, 0, stream>>>(packed, SO, part, offC, (unsigned short*)list2P, N, nb1, M, E);
    if (VPREC) k_aggV<1,unsigned short><<<dim3(2048), blk, 0, stream>>>(uh, vf, vh, vf, vh, msgb1, msgW2, msgb2, offC, (unsigned short*)list2P, N);
    else       k_aggV<0,unsigned short><<<dim3(2048), blk, 0, stream>>>(uh, vf, vh, vf, vh, msgb1, msgW2, msgb2, offC, (unsigned short*)list2P, N);
  } else {
    k_pass3<int><<<dim3(nb1), blk, 0, stream>>>(packed, SO, part, offC, (int*)list2P, N, nb1, M, E);
    if (VPREC) k_aggV<1,int><<<dim3(2048), blk, 0, stream>>>(uh, vf, vh, vf, vh, msgb1, msgW2, msgb2, offC, (int*)list2P, N);
    else       k_aggV<0,int><<<dim3(2048), blk, 0, stream>>>(uh, vf, vh, vf, vh, msgb1, msgW2, msgb2, offC, (int*)list2P, N);
  }
  if (VPREC) k_upd1<1><<<dim3(2048), blk, 0, stream>>>(hb, vf, vh, updW1, updb1, updW2, updb2, out, N);
  else       k_upd1<0><<<dim3(2048), blk, 0, stream>>>(hb, vf, vh, updW1, updb1, updW2, updb2, out, N);
  k_tac<<<dim3(nblkN), blk, 0, stream>>>(tacW1, tacb1, tacW2, tacb2, tacW3, tacb3, out, N);
}